// Round 1
// baseline (437.715 us; speedup 1.0000x reference)
//
#include <hip/hip_runtime.h>
#include <stdint.h>

#define B_ 4096
#define T_ 49
#define H_ 512
#define BT_ (B_*T_)
#define BB 16

typedef __bf16 bf16x8 __attribute__((ext_vector_type(8)));
typedef float  f32x4  __attribute__((ext_vector_type(4)));

__device__ __forceinline__ unsigned short f2bf(float f){
  unsigned int u = __float_as_uint(f);
  u += 0x7fffu + ((u >> 16) & 1u);           // RNE
  return (unsigned short)(u >> 16);
}

__device__ __forceinline__ float fast_tanh(float x){
  float e = __expf(2.0f * x);
  return 1.0f - 2.0f * __builtin_amdgcn_rcpf(e + 1.0f);
}

// K0: W_v [K][N] f32 -> WvT [N][K] bf16 (so MFMA B-frags are contiguous 16B loads)
__global__ __launch_bounds__(256) void k_wvt(const float* __restrict__ Wv,
                                             unsigned short* __restrict__ wvt){
  int idx = blockIdx.x * 256 + threadIdx.x;  // 0..262143
  int k = idx & (H_-1);
  int n = idx >> 9;
  wvt[n*H_ + k] = f2bf(Wv[(size_t)k*H_ + n]);
}

// K1: hpb[b][k] = h@W_h + b_h + b_v ; beta[b] = tanh((s@W_s + b_s + h_proj)*sqrt(.5))@w_beta + b_beta
__global__ __launch_bounds__(512) void k_proj(
    const float* __restrict__ h, const float* __restrict__ s,
    const float* __restrict__ Wh, const float* __restrict__ bh,
    const float* __restrict__ Ws, const float* __restrict__ bs,
    const float* __restrict__ bv, const float* __restrict__ wbeta,
    const float* __restrict__ bbeta_p,
    float* __restrict__ hpb, float* __restrict__ beta)
{
  __shared__ float hs[H_*BB];     // [j][bb] layout
  __shared__ float ssm[H_*BB];
  __shared__ float part[BB][8];
  const int tid = threadIdx.x;
  const int b0 = blockIdx.x * BB;

  for(int idx = tid; idx < H_*BB; idx += 512){
    int bb2 = idx & (BB-1);
    int j   = idx >> 4;
    hs[idx]  = h[(size_t)(b0+bb2)*H_ + j];
    ssm[idx] = s[(size_t)(b0+bb2)*H_ + j];
  }
  __syncthreads();

  const int k = tid;
  float ah[BB], as_[BB];
  #pragma unroll
  for(int i=0;i<BB;i++){ ah[i]=0.f; as_[i]=0.f; }

  #pragma unroll 4
  for(int j=0;j<H_;j++){
    float whv = Wh[j*H_ + k];
    float wsv = Ws[j*H_ + k];
    #pragma unroll
    for(int i=0;i<BB;i++){
      ah[i]  = fmaf(hs[j*BB+i],  whv, ah[i]);
      as_[i] = fmaf(ssm[j*BB+i], wsv, as_[i]);
    }
  }

  const float bhk = bh[k], bsk = bs[k], bvk = bv[k], wbk = wbeta[k];
  const float bbv = bbeta_p[0];
  const int lane = tid & 63, wid = tid >> 6;

  #pragma unroll
  for(int i=0;i<BB;i++){
    float hp = ah[i] + bhk;
    hpb[(size_t)(b0+i)*H_ + k] = hp + bvk;
    float bt = fast_tanh((as_[i] + bsk + hp) * 0.70710678118654752f);
    float c = bt * wbk;
    #pragma unroll
    for(int m=32;m>=1;m>>=1) c += __shfl_xor(c, m);
    if(lane == 0) part[i][wid] = c;
  }
  __syncthreads();
  if(tid < BB){
    float acc = bbv;
    #pragma unroll
    for(int wq=0; wq<8; wq++) acc += part[tid][wq];
    beta[b0+tid] = acc;
  }
}

// K2: per block, 64 rows of v (bf16 in LDS, swizzled) x full N=512 via WvT from L2.
// Epilogue: z[row] = sum_n w_z[n]*tanh(hpb[b][n] + vproj) + b_z  (complete rows, no atomics)
__global__ __launch_bounds__(256, 2) void k_gemm(
    const float* __restrict__ v, const unsigned short* __restrict__ wvt,
    const float* __restrict__ hpb, const float* __restrict__ wz,
    const float* __restrict__ bz_p, float* __restrict__ zout)
{
  __shared__ unsigned short Asm_[64 * H_];   // 64 KiB bf16, XOR-swizzled
  const int tid = threadIdx.x;
  const int gr0 = blockIdx.x * 64;

  { // stage A: 64x512 f32 -> bf16 LDS; swizzle byte ^= (row&7)<<4
    const float4* vsrc = (const float4*)(v + (size_t)gr0 * H_);
    #pragma unroll
    for(int it = 0; it < 32; ++it){
      int flat = tid + it * 256;            // float4 index in [64][128]
      int r  = flat >> 7;
      int k4 = (flat & 127) << 2;           // f32 column
      float4 f = vsrc[flat];
      ushort4 uq;
      uq.x = f2bf(f.x); uq.y = f2bf(f.y); uq.z = f2bf(f.z); uq.w = f2bf(f.w);
      int byte = ((r << 10) | (k4 << 1)) ^ ((r & 7) << 4);
      *(ushort4*)((char*)Asm_ + byte) = uq;
    }
  }
  __syncthreads();

  const int w = tid >> 6, lane = tid & 63;
  const int l15 = lane & 15, l4 = lane >> 4;
  const int nw0 = w << 7;                    // wave's 128-col slice

  const bf16x8* __restrict__ bsrc = (const bf16x8*)wvt;
  int bbase[8];
  #pragma unroll
  for(int ni=0;ni<8;ni++) bbase[ni] = (nw0 + ni*16 + l15)*64 + l4;

  f32x4 acc[4][8];
  #pragma unroll
  for(int mi=0;mi<4;mi++)
    #pragma unroll
    for(int ni=0;ni<8;ni++) acc[mi][ni] = (f32x4){0.f,0.f,0.f,0.f};

  bf16x8 ba[8], bbuf[8];
  #pragma unroll
  for(int ni=0;ni<8;ni++) ba[ni] = bsrc[bbase[ni]];        // ks=0

  #pragma unroll 1
  for(int ks2 = 0; ks2 < 8; ++ks2){
    const int ks0 = ks2*2, ks1 = ks0+1, ksn = (ks0+2) & 15;
    bf16x8 af[4];
    // phase A: prefetch B for ks1, compute ks0 with ba
    #pragma unroll
    for(int ni=0;ni<8;ni++) bbuf[ni] = bsrc[bbase[ni] + ks1*4];
    #pragma unroll
    for(int mi=0;mi<4;mi++){
      int row = mi*16 + l15;
      int byte = ((row<<10) | (ks0<<6) | (l4<<4)) ^ ((row&7)<<4);
      af[mi] = *(const bf16x8*)((const char*)Asm_ + byte);
    }
    #pragma unroll
    for(int mi=0;mi<4;mi++)
      #pragma unroll
      for(int ni=0;ni<8;ni++)
        acc[mi][ni] = __builtin_amdgcn_mfma_f32_16x16x32_bf16(af[mi], ba[ni], acc[mi][ni], 0,0,0);
    // phase B: prefetch B for next even step, compute ks1 with bbuf
    #pragma unroll
    for(int ni=0;ni<8;ni++) ba[ni] = bsrc[bbase[ni] + ksn*4];
    #pragma unroll
    for(int mi=0;mi<4;mi++){
      int row = mi*16 + l15;
      int byte = ((row<<10) | (ks1<<6) | (l4<<4)) ^ ((row&7)<<4);
      af[mi] = *(const bf16x8*)((const char*)Asm_ + byte);
    }
    #pragma unroll
    for(int mi=0;mi<4;mi++)
      #pragma unroll
      for(int ni=0;ni<8;ni++)
        acc[mi][ni] = __builtin_amdgcn_mfma_f32_16x16x32_bf16(af[mi], bbuf[ni], acc[mi][ni], 0,0,0);
  }

  // epilogue: z-partials. rows gr0..gr0+63 span at most 3 batch indices.
  const int b0 = gr0 / T_;
  const int b1 = min(b0+1, B_-1);
  const int b2 = min(b0+2, B_-1);
  float wzv[8], hp0[8], hp1[8], hp2[8];
  #pragma unroll
  for(int ni=0;ni<8;ni++){
    int col = nw0 + ni*16 + l15;
    wzv[ni] = wz[col];
    hp0[ni] = hpb[(size_t)b0*H_ + col];
    hp1[ni] = hpb[(size_t)b1*H_ + col];
    hp2[ni] = hpb[(size_t)b2*H_ + col];
  }
  float zp[16];
  #pragma unroll
  for(int mi=0;mi<4;mi++){
    #pragma unroll
    for(int r=0;r<4;r++){
      int rowl = mi*16 + l4*4 + r;            // C/D: col=l&15, row=(l>>4)*4+reg
      int bb2  = (gr0 + rowl)/T_ - b0;        // 0..2
      float az = 0.f;
      #pragma unroll
      for(int ni=0;ni<8;ni++){
        float hpv = (bb2==0) ? hp0[ni] : ((bb2==1) ? hp1[ni] : hp2[ni]);
        float x = acc[mi][ni][r] + hpv;
        az = fmaf(fast_tanh(x), wzv[ni], az);
      }
      zp[mi*4+r] = az;
    }
  }
  #pragma unroll
  for(int i=0;i<16;i++){
    zp[i] += __shfl_xor(zp[i], 1);
    zp[i] += __shfl_xor(zp[i], 2);
    zp[i] += __shfl_xor(zp[i], 4);
    zp[i] += __shfl_xor(zp[i], 8);
  }
  __syncthreads();                            // done reading Asm_
  float* zw = (float*)Asm_;                   // reuse LDS: [4 waves][64 rows]
  if(l15 == 0){
    #pragma unroll
    for(int mi=0;mi<4;mi++)
      #pragma unroll
      for(int r=0;r<4;r++)
        zw[w*64 + mi*16 + l4*4 + r] = zp[mi*4+r];
  }
  __syncthreads();
  if(tid < 64){
    float sum_ = zw[tid] + zw[64+tid] + zw[128+tid] + zw[192+tid] + bz_p[0];
    zout[gr0 + tid] = sum_;
  }
}

// K3: softmax over [z(49), beta] then c[b] = sum_t a_t v[b,t] + a_49 s[b]
__global__ __launch_bounds__(256) void k_out(
    const float* __restrict__ v, const float* __restrict__ s,
    const float* __restrict__ z, const float* __restrict__ beta,
    float* __restrict__ out)
{
  const int b = blockIdx.x;
  const int tid = threadIdx.x;
  __shared__ float a_s[64];
  if(tid < 64){
    float zv = -3.0e38f;
    if(tid < T_)       zv = z[b*T_ + tid];
    else if(tid == T_) zv = beta[b];
    float m = zv;
    #pragma unroll
    for(int off=32;off>=1;off>>=1) m = fmaxf(m, __shfl_xor(m, off));
    float e = (tid <= T_) ? __expf(zv - m) : 0.f;
    float ssum = e;
    #pragma unroll
    for(int off=32;off>=1;off>>=1) ssum += __shfl_xor(ssum, off);
    a_s[tid] = e * __builtin_amdgcn_rcpf(ssum);
  }
  __syncthreads();

  const float2* vb = (const float2*)(v + (size_t)b*T_*H_);
  float ax = 0.f, ay = 0.f;
  #pragma unroll 7
  for(int t=0;t<T_;t++){
    float at = a_s[t];
    float2 vv = vb[t*256 + tid];
    ax = fmaf(at, vv.x, ax);
    ay = fmaf(at, vv.y, ay);
  }
  float a49 = a_s[T_];
  float2 sv = ((const float2*)(s + (size_t)b*H_))[tid];
  ax = fmaf(a49, sv.x, ax);
  ay = fmaf(a49, sv.y, ay);
  float2 res; res.x = ax; res.y = ay;
  ((float2*)(out + (size_t)b*H_))[tid] = res;
}

extern "C" void kernel_launch(void* const* d_in, const int* in_sizes, int n_in,
                              void* d_out, int out_size, void* d_ws, size_t ws_size,
                              hipStream_t stream)
{
  const float* v   = (const float*)d_in[0];
  const float* h   = (const float*)d_in[1];
  const float* s   = (const float*)d_in[2];
  const float* Wh  = (const float*)d_in[3];
  const float* bh  = (const float*)d_in[4];
  const float* Wv  = (const float*)d_in[5];
  const float* bv  = (const float*)d_in[6];
  const float* wz  = (const float*)d_in[7];
  const float* bz  = (const float*)d_in[8];
  const float* Ws  = (const float*)d_in[9];
  const float* bs  = (const float*)d_in[10];
  const float* wb  = (const float*)d_in[11];
  const float* bbet= (const float*)d_in[12];
  float* out = (float*)d_out;

  // workspace layout (all written before read; ~9.8 MB)
  float* hpb  = (float*)d_ws;                      // B*H f32
  float* z    = hpb + (size_t)B_*H_;               // B*T f32
  float* beta = z + BT_;                           // B f32
  unsigned short* wvt = (unsigned short*)(beta + B_); // H*H bf16 (16B-aligned)

  k_wvt <<<(H_*H_)/256, 256, 0, stream>>>(Wv, wvt);
  k_proj<<<B_/BB, 512, 0, stream>>>(h, s, Wh, bh, Ws, bs, bv, wb, bbet, hpb, beta);
  k_gemm<<<BT_/64, 256, 0, stream>>>(v, wvt, hpb, wz, bz, z);
  k_out <<<B_, 256, 0, stream>>>(v, s, z, beta, out);
}

// Round 2
// 338.319 us; speedup vs baseline: 1.2938x; 1.2938x over previous
//
#include <hip/hip_runtime.h>
#include <stdint.h>

#define B_ 4096
#define T_ 49
#define H_ 512
#define BT_ (B_*T_)
#define BB 16
#define RB 64

typedef __bf16 bf16x8 __attribute__((ext_vector_type(8)));
typedef float  f32x4  __attribute__((ext_vector_type(4)));
typedef unsigned short ushort_;

__device__ __forceinline__ ushort_ f2bf(float f){
  unsigned int u = __float_as_uint(f);
  u += 0x7fffu + ((u >> 16) & 1u);           // RNE
  return (ushort_)(u >> 16);
}

__device__ __forceinline__ float fast_tanh(float x){
  float e = __expf(2.0f * x);
  return 1.0f - 2.0f * __builtin_amdgcn_rcpf(e + 1.0f);
}

// k_pack: Wv [K][N] f32 -> fragment-ordered bf16.
// bpack[((kk*32 + gt)*64 + lane)*8 + e] = bf16(Wv[kk*32 + (lane>>4)*8 + e][gt*16 + (lane&15)])
// so a B-frag load for (kk, global ntile gt) is lane-contiguous 16B -> 1KB coalesced.
__global__ __launch_bounds__(256) void k_pack(const float* __restrict__ Wv,
                                              ushort_* __restrict__ bpack){
  int idx = blockIdx.x * 256 + threadIdx.x;   // 0..32767
  int lane = idx & 63;
  int gt   = (idx >> 6) & 31;
  int kk   = idx >> 11;
  int col  = gt*16 + (lane & 15);
  int k0   = kk*32 + (lane >> 4)*8;
  ushort4 lo, hi;
  lo.x = f2bf(Wv[(k0+0)*H_ + col]);
  lo.y = f2bf(Wv[(k0+1)*H_ + col]);
  lo.z = f2bf(Wv[(k0+2)*H_ + col]);
  lo.w = f2bf(Wv[(k0+3)*H_ + col]);
  hi.x = f2bf(Wv[(k0+4)*H_ + col]);
  hi.y = f2bf(Wv[(k0+5)*H_ + col]);
  hi.z = f2bf(Wv[(k0+6)*H_ + col]);
  hi.w = f2bf(Wv[(k0+7)*H_ + col]);
  ushort4* dst = (ushort4*)bpack;
  dst[idx*2]   = lo;
  dst[idx*2+1] = hi;
}

// K1: hpb[b][k] = h@W_h + b_h + b_v ; beta[b] = tanh((s@W_s + b_s + h_proj)*sqrt(.5))@w_beta + b_beta
__global__ __launch_bounds__(512) void k_proj(
    const float* __restrict__ h, const float* __restrict__ s,
    const float* __restrict__ Wh, const float* __restrict__ bh,
    const float* __restrict__ Ws, const float* __restrict__ bs,
    const float* __restrict__ bv, const float* __restrict__ wbeta,
    const float* __restrict__ bbeta_p,
    float* __restrict__ hpb, float* __restrict__ beta)
{
  __shared__ float hs[H_*BB];     // [j][bb] layout
  __shared__ float ssm[H_*BB];
  __shared__ float part[BB][8];
  const int tid = threadIdx.x;
  const int b0 = blockIdx.x * BB;

  for(int idx = tid; idx < H_*BB; idx += 512){
    int bb2 = idx & (BB-1);
    int j   = idx >> 4;
    hs[idx]  = h[(size_t)(b0+bb2)*H_ + j];
    ssm[idx] = s[(size_t)(b0+bb2)*H_ + j];
  }
  __syncthreads();

  const int k = tid;
  float ah[BB], as_[BB];
  #pragma unroll
  for(int i=0;i<BB;i++){ ah[i]=0.f; as_[i]=0.f; }

  #pragma unroll 4
  for(int j=0;j<H_;j++){
    float whv = Wh[j*H_ + k];
    float wsv = Ws[j*H_ + k];
    #pragma unroll
    for(int i=0;i<BB;i++){
      ah[i]  = fmaf(hs[j*BB+i],  whv, ah[i]);
      as_[i] = fmaf(ssm[j*BB+i], wsv, as_[i]);
    }
  }

  const float bhk = bh[k], bsk = bs[k], bvk = bv[k], wbk = wbeta[k];
  const float bbv = bbeta_p[0];
  const int lane = tid & 63, wid = tid >> 6;

  #pragma unroll
  for(int i=0;i<BB;i++){
    float hp = ah[i] + bhk;
    hpb[(size_t)(b0+i)*H_ + k] = hp + bvk;
    float bt = fast_tanh((as_[i] + bsk + hp) * 0.70710678118654752f);
    float c = bt * wbk;
    #pragma unroll
    for(int m=32;m>=1;m>>=1) c += __shfl_xor(c, m);
    if(lane == 0) part[i][wid] = c;
  }
  __syncthreads();
  if(tid < BB){
    float acc = bbv;
    #pragma unroll
    for(int wq=0; wq<8; wq++) acc += part[tid][wq];
    beta[b0+tid] = acc;
  }
}

// K2: 64 rows x full N=512 per block. A pipelined through 2x8KB LDS in BK=64
// chunks (issue-early loads, write-late, 1 barrier/chunk). B register-prefetched
// from frag-packed L2-resident bpack (coalesced 1KB loads).
// Epilogue: z[row] = sum_n w_z[n]*tanh(hpb[b][n] + acc) + b_z
__global__ __launch_bounds__(256, 2) void k_gemm(
    const float* __restrict__ v, const ushort_* __restrict__ bpack,
    const float* __restrict__ hpb, const float* __restrict__ wz,
    const float* __restrict__ bz_p, float* __restrict__ zout)
{
  __shared__ __align__(16) ushort_ Abuf[2][RB*64];   // 2 x 8KB bf16, swizzled granules
  const int tid = threadIdx.x;
  const int w = tid >> 6, lane = tid & 63;
  const int l15 = lane & 15, l4 = lane >> 4;
  const int gr0 = blockIdx.x * RB;

  const float4* __restrict__ vsrc = (const float4*)(v + (size_t)gr0 * H_);
  const bf16x8* __restrict__ bp = (const bf16x8*)bpack;
  const int bbase = w*512 + lane;            // + kk*2048 + ni*64

  // stage thread mapping: load i covers float4 fidx=i*256+tid of the 64x64 chunk
  int vidx[4], wbyte[4];
  const int c4 = tid & 15;
  #pragma unroll
  for(int i=0;i<4;i++){
    int row = i*16 + (tid >> 4);
    vidx[i]  = row*128 + c4;                 // float4 units; + c*16 per chunk
    wbyte[i] = row*128 + ((((c4>>1) ^ (row&7))<<4) | ((c4&1)<<3));
  }
  // A-frag read offsets (row&7 == l15&7 for all mi)
  const int rslot0 = ((l4     ^ (l15 & 7)) << 4);
  const int rslot1 = (((4+l4) ^ (l15 & 7)) << 4);
  const int rbase  = l15 * 128;              // + mi*2048

  // ---- prologue: stage chunk 0, load B(kk=0)
  #pragma unroll
  for(int i=0;i<4;i++){
    float4 f = vsrc[vidx[i]];
    ushort4 u; u.x=f2bf(f.x); u.y=f2bf(f.y); u.z=f2bf(f.z); u.w=f2bf(f.w);
    *(ushort4*)((char*)Abuf[0] + wbyte[i]) = u;
  }

  f32x4 acc[4][8];
  #pragma unroll
  for(int mi=0;mi<4;mi++)
    #pragma unroll
    for(int ni=0;ni<8;ni++) acc[mi][ni] = (f32x4){0.f,0.f,0.f,0.f};

  bf16x8 ba[8], bb[8];
  #pragma unroll
  for(int ni=0;ni<8;ni++) ba[ni] = bp[bbase + ni*64];
  __syncthreads();

  // ---- main loop: 8 chunks of BK=64 (two 32-K MFMA steps each)
  #pragma unroll 1
  for(int c=0;c<8;c++){
    float4 nf0, nf1, nf2, nf3;
    if(c < 7){                               // issue next chunk's loads EARLY
      nf0 = vsrc[vidx[0] + (c+1)*16];
      nf1 = vsrc[vidx[1] + (c+1)*16];
      nf2 = vsrc[vidx[2] + (c+1)*16];
      nf3 = vsrc[vidx[3] + (c+1)*16];
    }
    const char* ab = (const char*)Abuf[c&1];
    bf16x8 af[4];

    // K-step 0 (kk=2c): prefetch B for kk=2c+1, compute with ba
    #pragma unroll
    for(int ni=0;ni<8;ni++) bb[ni] = bp[(2*c+1)*2048 + bbase + ni*64];
    #pragma unroll
    for(int mi=0;mi<4;mi++) af[mi] = *(const bf16x8*)(ab + mi*2048 + rbase + rslot0);
    #pragma unroll
    for(int mi=0;mi<4;mi++)
      #pragma unroll
      for(int ni=0;ni<8;ni++)
        acc[mi][ni] = __builtin_amdgcn_mfma_f32_16x16x32_bf16(af[mi], ba[ni], acc[mi][ni], 0,0,0);

    // K-step 1 (kk=2c+1): prefetch B for kk=2c+2, compute with bb
    if(c < 7){
      #pragma unroll
      for(int ni=0;ni<8;ni++) ba[ni] = bp[(2*c+2)*2048 + bbase + ni*64];
    }
    #pragma unroll
    for(int mi=0;mi<4;mi++) af[mi] = *(const bf16x8*)(ab + mi*2048 + rbase + rslot1);
    #pragma unroll
    for(int mi=0;mi<4;mi++)
      #pragma unroll
      for(int ni=0;ni<8;ni++)
        acc[mi][ni] = __builtin_amdgcn_mfma_f32_16x16x32_bf16(af[mi], bb[ni], acc[mi][ni], 0,0,0);

    // write staged chunk (late — loads had the whole compute phase to land)
    if(c < 7){
      ushort_* wb = (ushort_*)Abuf[(c+1)&1];
      float4 nf[4] = {nf0, nf1, nf2, nf3};
      #pragma unroll
      for(int i=0;i<4;i++){
        ushort4 u; u.x=f2bf(nf[i].x); u.y=f2bf(nf[i].y); u.z=f2bf(nf[i].z); u.w=f2bf(nf[i].w);
        *(ushort4*)((char*)wb + wbyte[i]) = u;
      }
    }
    __syncthreads();
  }

  // ---- epilogue: z[row] = sum_cols wz*tanh(acc + hpb) + bz
  const int b0 = gr0 / T_;
  const int b1 = min(b0+1, B_-1);
  const int b2 = min(b0+2, B_-1);
  float wzv[8], hp0[8], hp1[8], hp2[8];
  #pragma unroll
  for(int ni=0;ni<8;ni++){
    int col = w*128 + ni*16 + l15;
    wzv[ni] = wz[col];
    hp0[ni] = hpb[(size_t)b0*H_ + col];
    hp1[ni] = hpb[(size_t)b1*H_ + col];
    hp2[ni] = hpb[(size_t)b2*H_ + col];
  }
  float zp[16];
  #pragma unroll
  for(int mi=0;mi<4;mi++){
    #pragma unroll
    for(int r=0;r<4;r++){
      int rowl = mi*16 + l4*4 + r;            // C/D: col=l&15, row=(l>>4)*4+reg
      int bb2  = (gr0 + rowl)/T_ - b0;        // 0..2
      float az = 0.f;
      #pragma unroll
      for(int ni=0;ni<8;ni++){
        float hpv = (bb2==0) ? hp0[ni] : ((bb2==1) ? hp1[ni] : hp2[ni]);
        float x = acc[mi][ni][r] + hpv;
        az = fmaf(fast_tanh(x), wzv[ni], az);
      }
      zp[mi*4+r] = az;
    }
  }
  #pragma unroll
  for(int i=0;i<16;i++){
    zp[i] += __shfl_xor(zp[i], 1);
    zp[i] += __shfl_xor(zp[i], 2);
    zp[i] += __shfl_xor(zp[i], 4);
    zp[i] += __shfl_xor(zp[i], 8);
  }
  __syncthreads();                            // done with Abuf
  float* zw = (float*)Abuf;                   // reuse LDS: [4 waves][64 rows]
  if(l15 == 0){
    #pragma unroll
    for(int mi=0;mi<4;mi++)
      #pragma unroll
      for(int r=0;r<4;r++)
        zw[w*64 + mi*16 + l4*4 + r] = zp[mi*4+r];
  }
  __syncthreads();
  if(tid < 64){
    float sum_ = zw[tid] + zw[64+tid] + zw[128+tid] + zw[192+tid] + bz_p[0];
    zout[gr0 + tid] = sum_;
  }
}

// K3: softmax over [z(49), beta] then c[b] = sum_t a_t v[b,t] + a_49 s[b]
__global__ __launch_bounds__(256) void k_out(
    const float* __restrict__ v, const float* __restrict__ s,
    const float* __restrict__ z, const float* __restrict__ beta,
    float* __restrict__ out)
{
  const int b = blockIdx.x;
  const int tid = threadIdx.x;
  __shared__ float a_s[64];
  if(tid < 64){
    float zv = -3.0e38f;
    if(tid < T_)       zv = z[b*T_ + tid];
    else if(tid == T_) zv = beta[b];
    float m = zv;
    #pragma unroll
    for(int off=32;off>=1;off>>=1) m = fmaxf(m, __shfl_xor(m, off));
    float e = (tid <= T_) ? __expf(zv - m) : 0.f;
    float ssum = e;
    #pragma unroll
    for(int off=32;off>=1;off>>=1) ssum += __shfl_xor(ssum, off);
    a_s[tid] = e * __builtin_amdgcn_rcpf(ssum);
  }
  __syncthreads();

  const float2* vb = (const float2*)(v + (size_t)b*T_*H_);
  float ax = 0.f, ay = 0.f;
  #pragma unroll 7
  for(int t=0;t<T_;t++){
    float at = a_s[t];
    float2 vv = vb[t*256 + tid];
    ax = fmaf(at, vv.x, ax);
    ay = fmaf(at, vv.y, ay);
  }
  float a49 = a_s[T_];
  float2 sv = ((const float2*)(s + (size_t)b*H_))[tid];
  ax = fmaf(a49, sv.x, ax);
  ay = fmaf(a49, sv.y, ay);
  float2 res; res.x = ax; res.y = ay;
  ((float2*)(out + (size_t)b*H_))[tid] = res;
}

extern "C" void kernel_launch(void* const* d_in, const int* in_sizes, int n_in,
                              void* d_out, int out_size, void* d_ws, size_t ws_size,
                              hipStream_t stream)
{
  const float* v   = (const float*)d_in[0];
  const float* h   = (const float*)d_in[1];
  const float* s   = (const float*)d_in[2];
  const float* Wh  = (const float*)d_in[3];
  const float* bh  = (const float*)d_in[4];
  const float* Wv  = (const float*)d_in[5];
  const float* bv  = (const float*)d_in[6];
  const float* wz  = (const float*)d_in[7];
  const float* bz  = (const float*)d_in[8];
  const float* Ws  = (const float*)d_in[9];
  const float* bs  = (const float*)d_in[10];
  const float* wb  = (const float*)d_in[11];
  const float* bbet= (const float*)d_in[12];
  float* out = (float*)d_out;

  // workspace layout (all written before read; ~9.3 MB)
  float* hpb  = (float*)d_ws;                      // B*H f32
  float* z    = hpb + (size_t)B_*H_;               // B*T f32
  float* beta = z + BT_;                           // B f32
  ushort_* bpack = (ushort_*)(beta + B_);          // 512KB frag-packed bf16

  k_pack<<<128, 256, 0, stream>>>(Wv, bpack);
  k_proj<<<B_/BB, 512, 0, stream>>>(h, s, Wh, bh, Ws, bs, bv, wb, bbet, hpb, beta);
  k_gemm<<<BT_/RB, 256, 0, stream>>>(v, bpack, hpb, wz, bz, z);
  k_out <<<B_, 256, 0, stream>>>(v, s, z, beta, out);
}